// Round 4
// baseline (262.587 us; speedup 1.0000x reference)
//
#include <hip/hip_runtime.h>

// Problem constants (match reference)
constexpr int B = 1024, N = 100, C = 256, K = 3;
constexpr int ROWS = B * N;                      // 102400
constexpr int THREADS = 256;
constexpr int WAVES_PER_BLOCK = THREADS / 64;    // 4
constexpr int BLOCKS = 2048;                     // 8 blocks/CU on 256 CUs
constexpr int TOTAL_WAVES = BLOCKS * WAVES_PER_BLOCK;  // 8192 persistent waves
constexpr float LN_EPS = 1e-5f;

typedef float f32x4 __attribute__((ext_vector_type(4)));

// DPP row_ror:n — lane i <- lane (i-n) mod 16 within each 16-lane row.
// (Proven on this harness in round 1.)
template <int N_>
__device__ __forceinline__ float fror(float x) {
    return __int_as_float(__builtin_amdgcn_update_dpp(
        0, __float_as_int(x), 0x120 | N_, 0xF, 0xF, false));
}

// Full 64-lane sum: 4 DPP row_ror stages (VALU) + 2 shfl_xor stages (DS).
// All lanes end with the total.
__device__ __forceinline__ float wavesum(float x) {
    x += fror<1>(x);
    x += fror<2>(x);
    x += fror<4>(x);
    x += fror<8>(x);          // every lane now holds its 16-group sum
    x += __shfl_xor(x, 16);
    x += __shfl_xor(x, 32);
    return x;
}

__global__ __launch_bounds__(256) void dydwconv_ln_kernel(
    const float* __restrict__ query,   // [B,N,C]
    const float* __restrict__ value,   // [B,N,C]
    const float* __restrict__ Ww,      // [K,C]
    const float* __restrict__ bw,      // [K]
    const float* __restrict__ gamma,   // [C]
    const float* __restrict__ beta,    // [C]
    float* __restrict__ out)           // [B,N,C]
{
    const int t    = threadIdx.x;
    const int lane = t & 63;
    const int c0   = lane * 4;
    const int row0 = blockIdx.x * WAVES_PER_BLOCK + (t >> 6);  // first row for this wave

    // Rows this wave owns: row0, row0+TOTAL_WAVES, ...  (12 or 13 of them)
    const int nIter = (ROWS - row0 + TOTAL_WAVES - 1) / TOTAL_WAVES;

    // Per-lane constants, loaded ONCE per persistent wave (L1-hot, tiny).
    const float4 Wa = *(const float4*)(Ww + c0);
    const float4 Wb = *(const float4*)(Ww + C + c0);
    const float4 Wc = *(const float4*)(Ww + 2 * C + c0);
    const float4 g4 = *(const float4*)(gamma + c0);
    const float4 b4 = *(const float4*)(beta + c0);
    const float  b0 = bw[0], b1 = bw[1], b2 = bw[2];

    constexpr size_t STEP = (size_t)TOTAL_WAVES * C;
    size_t off = (size_t)row0 * C + c0;

    // Prologue: first row's loads in flight.
    float4 qc = *(const float4*)(query + off);
    float4 vc = *(const float4*)(value + off);

    for (int it = 0; it < nIter; ++it) {
        // Prefetch next row BEFORE consuming the current one: its HBM
        // latency hides under this row's reduction chains.
        const bool hn = (it + 1) < nIter;       // wave-uniform
        const size_t noff = off + STEP;
        float4 qn = qc, vn = vc;                // defined on all paths
        if (hn) {
            qn = *(const float4*)(query + noff);
            vn = *(const float4*)(value + noff);
        }

        // ---- dynamic kernel taps: p_k = sum_c q[c]*W[k][c] ----
        float p0 = qc.x * Wa.x + qc.y * Wa.y + qc.z * Wa.z + qc.w * Wa.w;
        float p1 = qc.x * Wb.x + qc.y * Wb.y + qc.z * Wb.z + qc.w * Wb.w;
        float p2 = qc.x * Wc.x + qc.y * Wc.y + qc.z * Wc.z + qc.w * Wc.w;
        const float w0 = wavesum(p0) + b0;
        const float w1 = wavesum(p1) + b1;
        const float w2 = wavesum(p2) + b2;

        // ---- K=3 depthwise conv along channels (zero-padded) ----
        float vl = __shfl_up(vc.w, 1);     // value[c0-1]
        float vr = __shfl_down(vc.x, 1);   // value[c0+4]
        if (lane == 0)  vl = 0.0f;
        if (lane == 63) vr = 0.0f;

        const float o0 = vl   * w0 + vc.x * w1 + vc.y * w2;
        const float o1 = vc.x * w0 + vc.y * w1 + vc.z * w2;
        const float o2 = vc.y * w0 + vc.z * w1 + vc.w * w2;
        const float o3 = vc.z * w0 + vc.w * w1 + vr   * w2;

        // ---- LayerNorm over C ----
        float s  = (o0 + o1) + (o2 + o3);
        float ss = o0 * o0 + o1 * o1 + o2 * o2 + o3 * o3;
        s  = wavesum(s);
        ss = wavesum(ss);
        const float mu  = s * (1.0f / C);
        const float var = ss * (1.0f / C) - mu * mu;
        const float inv = rsqrtf(var + LN_EPS);

        f32x4 r;
        r.x = (o0 - mu) * inv * g4.x + b4.x;
        r.y = (o1 - mu) * inv * g4.y + b4.y;
        r.z = (o2 - mu) * inv * g4.z + b4.z;
        r.w = (o3 - mu) * inv * g4.w + b4.w;
        // out is never re-read: NT store preserves input L3 residency.
        __builtin_nontemporal_store(r, (f32x4*)(out + off));

        off = noff;
        qc = qn;
        vc = vn;
    }
}

extern "C" void kernel_launch(void* const* d_in, const int* in_sizes, int n_in,
                              void* d_out, int out_size, void* d_ws, size_t ws_size,
                              hipStream_t stream) {
    const float* query = (const float*)d_in[0];
    const float* value = (const float*)d_in[1];
    const float* Ww    = (const float*)d_in[2];
    const float* bw    = (const float*)d_in[3];
    const float* gamma = (const float*)d_in[4];
    const float* beta  = (const float*)d_in[5];
    float* outp = (float*)d_out;

    dydwconv_ln_kernel<<<BLOCKS, THREADS, 0, stream>>>(
        query, value, Ww, bw, gamma, beta, outp);
}

// Round 5
// 256.546 us; speedup vs baseline: 1.0235x; 1.0235x over previous
//
#include <hip/hip_runtime.h>

// Problem constants (match reference)
constexpr int B = 1024, N = 100, C = 256, K = 3;
constexpr int ROWS = B * N;                       // 102400
constexpr int THREADS = 256;
constexpr int WAVES_PER_BLOCK = 4;
constexpr int RPW = 4;                            // rows per wave (Little's-law lever)
constexpr int ROWS_PER_BLOCK = WAVES_PER_BLOCK * RPW;   // 16
constexpr int BLOCKS = ROWS / ROWS_PER_BLOCK;     // 6400, exact
constexpr float LN_EPS = 1e-5f;

// 64-lane butterfly sum (round-0-proven): all lanes end with the total.
__device__ __forceinline__ float wavesum(float x) {
    #pragma unroll
    for (int off = 32; off > 0; off >>= 1) x += __shfl_xor(x, off);
    return x;
}

__global__ __launch_bounds__(256) void dydwconv_ln_kernel(
    const float* __restrict__ query,   // [B,N,C]
    const float* __restrict__ value,   // [B,N,C]
    const float* __restrict__ Ww,      // [K,C]
    const float* __restrict__ bw,      // [K]
    const float* __restrict__ gamma,   // [C]
    const float* __restrict__ beta,    // [C]
    float* __restrict__ out)           // [B,N,C]
{
    const int t    = threadIdx.x;
    const int lane = t & 63;
    const int c0   = lane * 4;
    const int wave = t >> 6;
    const int r0   = (blockIdx.x * WAVES_PER_BLOCK + wave) * RPW;  // 4 consecutive rows
    const size_t base0 = (size_t)r0 * C + c0;

    // Per-lane constants in registers (3KB tables stay L1-hot chip-wide).
    const float4 Wa = *(const float4*)(Ww + c0);
    const float4 Wb = *(const float4*)(Ww + C + c0);
    const float4 Wc = *(const float4*)(Ww + 2 * C + c0);
    const float4 g4 = *(const float4*)(gamma + c0);
    const float4 b4 = *(const float4*)(beta + c0);
    const float  b0 = bw[0], b1 = bw[1], b2 = bw[2];

    // ---- Issue ALL 8 row loads up front: 8 KB in flight per wave. ----
    float4 q[RPW], v[RPW];
    #pragma unroll
    for (int i = 0; i < RPW; ++i) {
        q[i] = *(const float4*)(query + base0 + (size_t)i * C);
        v[i] = *(const float4*)(value + base0 + (size_t)i * C);
    }

    // ---- Phase A: per-row tap partials (drains q[i] as it arrives). ----
    float p0[RPW], p1[RPW], p2[RPW];
    #pragma unroll
    for (int i = 0; i < RPW; ++i) {
        p0[i] = q[i].x * Wa.x + q[i].y * Wa.y + q[i].z * Wa.z + q[i].w * Wa.w;
        p1[i] = q[i].x * Wb.x + q[i].y * Wb.y + q[i].z * Wb.z + q[i].w * Wb.w;
        p2[i] = q[i].x * Wc.x + q[i].y * Wc.y + q[i].z * Wc.z + q[i].w * Wc.w;
    }

    // ---- Phase B: 12 independent 6-stage reduce chains, interleaved. ----
    float w0[RPW], w1[RPW], w2[RPW];
    #pragma unroll
    for (int i = 0; i < RPW; ++i) {
        w0[i] = wavesum(p0[i]) + b0;
        w1[i] = wavesum(p1[i]) + b1;
        w2[i] = wavesum(p2[i]) + b2;
    }

    // ---- Phase C: conv (K=3, zero-padded) + LN partials per row. ----
    float4 o[RPW];
    float s[RPW], ss[RPW];
    #pragma unroll
    for (int i = 0; i < RPW; ++i) {
        float vl = __shfl_up(v[i].w, 1);     // value[c0-1]
        float vr = __shfl_down(v[i].x, 1);   // value[c0+4]
        if (lane == 0)  vl = 0.0f;
        if (lane == 63) vr = 0.0f;
        o[i].x = vl     * w0[i] + v[i].x * w1[i] + v[i].y * w2[i];
        o[i].y = v[i].x * w0[i] + v[i].y * w1[i] + v[i].z * w2[i];
        o[i].z = v[i].y * w0[i] + v[i].z * w1[i] + v[i].w * w2[i];
        o[i].w = v[i].z * w0[i] + v[i].w * w1[i] + vr     * w2[i];
        s[i]  = (o[i].x + o[i].y) + (o[i].z + o[i].w);
        ss[i] = o[i].x * o[i].x + o[i].y * o[i].y
              + o[i].z * o[i].z + o[i].w * o[i].w;
    }

    // ---- Phase D: 8 independent reduce chains, interleaved. ----
    #pragma unroll
    for (int i = 0; i < RPW; ++i) {
        s[i]  = wavesum(s[i]);
        ss[i] = wavesum(ss[i]);
    }

    // ---- Phase E: normalize + store. ----
    #pragma unroll
    for (int i = 0; i < RPW; ++i) {
        const float mu  = s[i] * (1.0f / C);
        const float var = ss[i] * (1.0f / C) - mu * mu;
        const float inv = rsqrtf(var + LN_EPS);
        float4 r;
        r.x = (o[i].x - mu) * inv * g4.x + b4.x;
        r.y = (o[i].y - mu) * inv * g4.y + b4.y;
        r.z = (o[i].z - mu) * inv * g4.z + b4.z;
        r.w = (o[i].w - mu) * inv * g4.w + b4.w;
        *(float4*)(out + base0 + (size_t)i * C) = r;
    }
}

extern "C" void kernel_launch(void* const* d_in, const int* in_sizes, int n_in,
                              void* d_out, int out_size, void* d_ws, size_t ws_size,
                              hipStream_t stream) {
    const float* query = (const float*)d_in[0];
    const float* value = (const float*)d_in[1];
    const float* Ww    = (const float*)d_in[2];
    const float* bw    = (const float*)d_in[3];
    const float* gamma = (const float*)d_in[4];
    const float* beta  = (const float*)d_in[5];
    float* outp = (float*)d_out;

    dydwconv_ln_kernel<<<BLOCKS, THREADS, 0, stream>>>(
        query, value, Ww, bw, gamma, beta, outp);
}